// Round 14
// baseline (123.358 us; speedup 1.0000x reference)
//
#include <hip/hip_runtime.h>
#include <math.h>

// (N, Cin, Cout, S, H, W) = (4, 256, 256, 512, 64, 64)
#define NB 4
#define CC 256
#define SS 512
#define NL 6
#define SLOT_HW 65536   // 128 KB per weight slot, MFMA-A-fragment-packed

typedef __attribute__((ext_vector_type(8))) short s16x8;
typedef __attribute__((ext_vector_type(4))) float f32x4;
typedef __attribute__((ext_vector_type(2))) float f32x2;
typedef __attribute__((ext_vector_type(4))) unsigned short u16x4;

__device__ __forceinline__ unsigned short f2bf(float f) {
    unsigned u = __builtin_bit_cast(unsigned, f);
    u += 0x7FFFu + ((u >> 16) & 1u);
    return (unsigned short)(u >> 16);
}
// gelu_exact(x) ~= x*sigmoid(1.5957691216*(x+0.044715x^3)), |err|<3e-3
__device__ __forceinline__ float gelu_fast(float x) {
    float u = x * (1.0f + 0.044715f * x * x);
    float e = __expf(-1.5957691216f * u);
    return x * __builtin_amdgcn_rcpf(1.0f + e);
}

// Fragment-packed weight layout, per 256x256 GEMM slot (128 KB):
// fragment f = (m>>4)*8 + (k>>5); inside: halfword offset
//   ((k>>3)&3)*128 + (m&15)*8 + (k&7)
// wave A-fragment read = slot + f*512 + lane*8 (16 B/lane contiguous).

// ---------------------------------------------------------------------------
__global__ __launch_bounds__(256) void wmod_kernel(
    const float* __restrict__ y, const float* __restrict__ aw,
    const float* __restrict__ ab, const float* __restrict__ mw,
    unsigned short* __restrict__ wsBF)
{
    int w = threadIdx.x >> 6, lane = threadIdx.x & 63;
    int r = blockIdx.x*4 + w;      // 0 .. 6143
    int l = r >> 10;
    int b = (r >> 8) & 3;
    int o = r & 255;

    const float* awr = aw + (size_t)(l*CC + o)*SS;
    const float* yb  = y + (size_t)b*SS;
    float s = 0.f;
#pragma unroll
    for (int j = 0; j < 8; ++j) { int idx = lane + 64*j; s += awr[idx]*yb[idx]; }
#pragma unroll
    for (int off = 32; off; off >>= 1) s += __shfl_xor(s, off);
    float t = s + ab[l*CC + o] + 1.0f;

    const float* mwr = mw + (size_t)(l*CC + o)*CC;
    float wv[4]; float ss = 0.f;
#pragma unroll
    for (int u = 0; u < 4; ++u) { int j = lane + 64*u; wv[u] = mwr[j]*t; ss += wv[u]*wv[u]; }
#pragma unroll
    for (int off = 32; off; off >>= 1) ss += __shfl_xor(ss, off);
    float d = 1.0f / sqrtf(ss + 1e-8f);

    unsigned short* slot = wsBF + (size_t)(1 + l*NB + b)*SLOT_HW;
#pragma unroll
    for (int u = 0; u < 4; ++u) {
        int k = lane + 64*u;
        int f = (o >> 4)*8 + (k >> 5);
        int hw = f*512 + ((k >> 3) & 3)*128 + (o & 15)*8 + (k & 7);
        slot[hw] = f2bf(wv[u]*d);
    }
}

__global__ __launch_bounds__(256) void cwsplit_kernel(
    const float* __restrict__ cw, unsigned short* __restrict__ wsBF)
{
    int w = threadIdx.x >> 6, lane = threadIdx.x & 63;
    int m = blockIdx.x*4 + w;      // 0..255
#pragma unroll
    for (int u = 0; u < 4; ++u) {
        int k = lane + 64*u;
        int f = (m >> 4)*8 + (k >> 5);
        int hw = f*512 + ((k >> 3) & 3)*128 + (m & 15)*8 + (k & 7);
        wsBF[hw] = f2bf(cw[(size_t)m*CC + k]);
    }
}

// ---------------------------------------------------------------------------
// Fused: one block = (batch, 32-px half-strip, all 256 channels). Grid 512,
// 68 KB LDS -> 2 blocks/CU. Wave w owns m=[32w,32w+32), all n=32 (zero A
// duplication). B plain bf16; state y1/y2 fp32 in regs. Layer B (16 KB)
// double-buffered -> 1 barrier/layer; A L2->reg prefetch depth 3.
// r14: conv restructured to the SAME shape — stage full x (36 KB fp32) once,
// one transpose pass packs all conv-B frags into buf0, one 8-step MFMA phase
// => 2 conv barriers (was 8). Epilogue S2 moved to the dead xS region.
#define BFRAGL(buf, kq, nt, kcl) \
    (lds + (buf)*16384 + ((((kq)*2 + (nt))*2 + (kcl)))*1024)

__global__ __launch_bounds__(512, 4) void fused_kernel(
    const float* __restrict__ x, const float* __restrict__ cb,
    const unsigned short* __restrict__ wsBF, float* __restrict__ out)
{
    // LDS 69632 B: layer-B dbuf [0,32K) | conv region @32768: xS f32[256][36]
    // (36864 B) during conv staging, then S2 f32[128][33] (16896 B) in the
    // epilogue (xS dead by then). Conv B frags live in buf0.
    __shared__ __align__(16) unsigned char lds[69632];
    float* xS = (float*)(lds + 32768);
    float* S2 = (float*)(lds + 32768);

    const int tid  = threadIdx.x;
    const int lane = tid & 63;
    const int w    = tid >> 6;     // wave 0..7: owns m-rows [32w, 32w+32)
    const int l15  = lane & 15;
    const int q    = lane >> 4;    // 0..3

    // XCD swizzle: blockIdx%8 -> (batch, half) per XCD; weights L2-resident
    const int bswz  = blockIdx.x & 7;
    const int b     = bswz >> 1;               // 0..3
    const int half  = bswz & 1;                // 0..1
    const int strip = blockIdx.x >> 3;         // 0..63
    const int n0    = strip * 64 + half * 32;  // 32-px window

    float y1[2][2][4], y2[2][2][4];
    f32x4 acc[2][2];

    // ---------------- conv GEMM:  acc = cw @ x[b], single-shot ----------------
#pragma unroll
    for (int t = 0; t < 2; ++t)
#pragma unroll
        for (int s = 0; s < 2; ++s) acc[t][s] = 0;

    {   // stage FULL x window [256k x 32n] fp32, coalesced
#pragma unroll
        for (int p = 0; p < 4; ++p) {
            int row = (tid >> 3) + 64*p, c4 = (tid & 7) * 4;
            float4 v = *(const float4*)&x[((size_t)(b*CC + row))*4096 + n0 + c4];
            *(float4*)&xS[row*36 + c4] = v;
        }
    }
    __syncthreads();
    {   // transpose-read (conflict-free) -> bf16 -> ALL conv-B frags (buf0)
        int n = tid & 31, k0 = (tid >> 5) * 16;
        int nt = n >> 4, n15 = n & 15;
#pragma unroll
        for (int j = 0; j < 4; ++j) {
            int k = k0 + 4*j;
            u16x4 hv;
#pragma unroll
            for (int i = 0; i < 4; ++i) hv[i] = f2bf(xS[(k+i)*36 + n]);
            int kq = k >> 6, kcl = (k >> 5) & 1, qq = (k >> 3) & 3, jb = k & 7;
            *(u16x4*)(BFRAGL(0,kq,nt,kcl) + (16*qq + n15)*16 + jb*2) = hv;
        }
    }
    {   // A prefetch (slot 0) depth 3, then one 8-step MFMA phase
        const unsigned short* slot = wsBF;
        s16x8 aS[8][2];
#pragma unroll
        for (int p = 0; p < 3; ++p)
#pragma unroll
        for (int t = 0; t < 2; ++t)
            aS[p][t] = *(const s16x8*)(slot + (size_t)(((2*w+t)*8 + p)*512) + lane*8);
        __syncthreads();
#pragma unroll
        for (int step = 0; step < 8; ++step) {
            if (step < 5) {
#pragma unroll
                for (int t = 0; t < 2; ++t)
                    aS[step+3][t] = *(const s16x8*)(slot + (size_t)(((2*w+t)*8 + step+3)*512) + lane*8);
            }
            int kq = step >> 1, kcl = step & 1;
#pragma unroll
            for (int s = 0; s < 2; ++s) {
                s16x8 bh = *(const s16x8*)(BFRAGL(0,kq,s,kcl) + lane*16);
#pragma unroll
                for (int t = 0; t < 2; ++t)
                    acc[t][s] = __builtin_amdgcn_mfma_f32_16x16x32_bf16(aS[step][t], bh, acc[t][s], 0, 0, 0);
            }
        }
    }

    // conv epilogue: bias + channel-duplication remap via S2 (xS region, dead).
    // x1[c] = conv[c>>1]+cb, x2[c] = conv[128+(c>>1)]+cb
#pragma unroll
    for (int pass = 0; pass < 2; ++pass) {
        __syncthreads();
        if ((w >> 2) == pass) {            // waves owning m in [128pass, +128)
#pragma unroll
            for (int t = 0; t < 2; ++t)
#pragma unroll
            for (int s = 0; s < 2; ++s)
#pragma unroll
            for (int r = 0; r < 4; ++r) {
                int m  = 32*w + 16*t + 4*q + r;
                int nl = 16*s + l15;
                S2[(m - 128*pass)*33 + nl] = acc[t][s][r] + cb[m];
            }
        }
        __syncthreads();
#pragma unroll
        for (int t = 0; t < 2; ++t)
#pragma unroll
        for (int s = 0; s < 2; ++s)
#pragma unroll
        for (int r = 0; r < 4; ++r) {
            int c  = 32*w + 16*t + 4*q + r;
            int nl = 16*s + l15;
            float v = S2[(c >> 1)*33 + nl];
            if (pass == 0) { y1[t][s][r] = v; }
            else           { y2[t][s][r] = v; y1[t][s][r] += v; }
        }
    }
    // y1 = x1+x2, y2 = x2.  No barrier needed: layer-0 staging targets buf0
    // [0,16K), disjoint from S2 @32768; buf0's conv reads were fenced by the
    // epilogue's first __syncthreads.

    // ---------------- 6 layers: ONE barrier per layer (B dbuf) ----------------
    for (int l = 0; l < NL; ++l) {
        const int buf = l & 1;
        const unsigned short* slot = wsBF + (size_t)(1 + l*NB + b)*SLOT_HW;
#pragma unroll
        for (int t = 0; t < 2; ++t)
#pragma unroll
            for (int s = 0; s < 2; ++s) acc[t][s] = 0;

        // stage B (bf16) from y1 regs: wave w's rows = k-slice [32w,32w+32)
        {
            int kq = w >> 1, kcl = w & 1, jb = 4*(q & 1);
#pragma unroll
            for (int t = 0; t < 2; ++t) {
                int qq = 2*t + (q >> 1);
#pragma unroll
                for (int s = 0; s < 2; ++s) {
                    u16x4 hv;
#pragma unroll
                    for (int r = 0; r < 4; ++r) hv[r] = f2bf(y1[t][s][r]);
                    *(u16x4*)(BFRAGL(buf,kq,s,kcl) + (16*qq + l15)*16 + jb*2) = hv;
                }
            }
        }
        // A prefetch pipeline, depth 3: issue steps 0..2 before the barrier
        s16x8 aS[8][2];
#pragma unroll
        for (int p = 0; p < 3; ++p)
#pragma unroll
        for (int t = 0; t < 2; ++t)
            aS[p][t] = *(const s16x8*)(slot + (size_t)(((2*w+t)*8 + p)*512) + lane*8);
        __syncthreads();
        // ONE long MFMA phase: 8 steps, A prefetched 3 steps ahead
#pragma unroll
        for (int step = 0; step < 8; ++step) {
            if (step < 5) {
#pragma unroll
                for (int t = 0; t < 2; ++t)
                    aS[step+3][t] = *(const s16x8*)(slot + (size_t)(((2*w+t)*8 + step+3)*512) + lane*8);
            }
            int kq = step >> 1, kcl = step & 1;
#pragma unroll
            for (int s = 0; s < 2; ++s) {
                s16x8 bh = *(const s16x8*)(BFRAGL(buf,kq,s,kcl) + lane*16);
#pragma unroll
                for (int t = 0; t < 2; ++t)
                    acc[t][s] = __builtin_amdgcn_mfma_f32_16x16x32_bf16(aS[step][t], bh, acc[t][s], 0, 0, 0);
            }
        }
        // y2 += gelu(h); y1 += y2 (next layer), skip on last.
        // No trailing barrier: next layer stages the OTHER buffer.
#pragma unroll
        for (int t = 0; t < 2; ++t)
#pragma unroll
        for (int s = 0; s < 2; ++s)
#pragma unroll
        for (int r = 0; r < 4; ++r) {
            y2[t][s][r] += gelu_fast(acc[t][s][r]);
            if (l < NL - 1) y1[t][s][r] += y2[t][s][r];
        }
    }

    // ---------------- out = 0.5*(y1+y2), 2x2 upsample (nontemporal) --------
#pragma unroll
    for (int t = 0; t < 2; ++t)
#pragma unroll
    for (int s = 0; s < 2; ++s)
#pragma unroll
    for (int r = 0; r < 4; ++r) {
        int ch  = 32*w + 16*t + 4*q + r;
        int wpx = half*32 + 16*s + l15;       // 0..63 source col
        float v = 0.5f*(y1[t][s][r] + y2[t][s][r]);
        f32x2 vv = {v, v};
        size_t base = (((size_t)(b*CC + ch)*128 + 2*strip))*128 + 2*wpx;
        __builtin_nontemporal_store(vv, (f32x2*)&out[base]);
        __builtin_nontemporal_store(vv, (f32x2*)&out[base + 128]);
    }
}

extern "C" void kernel_launch(void* const* d_in, const int* in_sizes, int n_in,
                              void* d_out, int out_size, void* d_ws, size_t ws_size,
                              hipStream_t stream) {
    const float* x  = (const float*)d_in[0];
    const float* y  = (const float*)d_in[1];
    const float* cw = (const float*)d_in[2];
    const float* cb = (const float*)d_in[3];
    const float* aw = (const float*)d_in[4];
    const float* ab = (const float*)d_in[5];
    const float* mw = (const float*)d_in[6];
    float* out = (float*)d_out;

    unsigned short* wsBF = (unsigned short*)d_ws;   // 25 slots * 128 KB = 3.2 MB

    wmod_kernel<<<NL*NB*CC/4, 256, 0, stream>>>(y, aw, ab, mw, wsBF);
    cwsplit_kernel<<<64, 256, 0, stream>>>(cw, wsBF);
    fused_kernel<<<512, 512, 0, stream>>>(x, cb, wsBF, out);
}

// Round 15
// 120.165 us; speedup vs baseline: 1.0266x; 1.0266x over previous
//
#include <hip/hip_runtime.h>
#include <math.h>

// (N, Cin, Cout, S, H, W) = (4, 256, 256, 512, 64, 64)
#define NB 4
#define CC 256
#define SS 512
#define NL 6
#define SLOT_HW 65536   // 128 KB per weight slot, MFMA-A-fragment-packed

typedef __attribute__((ext_vector_type(8))) short s16x8;
typedef __attribute__((ext_vector_type(4))) float f32x4;
typedef __attribute__((ext_vector_type(2))) float f32x2;
typedef __attribute__((ext_vector_type(4))) unsigned short u16x4;

__device__ __forceinline__ unsigned short f2bf(float f) {
    unsigned u = __builtin_bit_cast(unsigned, f);
    u += 0x7FFFu + ((u >> 16) & 1u);
    return (unsigned short)(u >> 16);
}
// gelu_exact(x) ~= x*sigmoid(1.5957691216*(x+0.044715x^3)), |err|<3e-3
__device__ __forceinline__ float gelu_fast(float x) {
    float u = x * (1.0f + 0.044715f * x * x);
    float e = __expf(-1.5957691216f * u);
    return x * __builtin_amdgcn_rcpf(1.0f + e);
}

// Fragment-packed weight layout, per 256x256 GEMM slot (128 KB):
// fragment f = (m>>4)*8 + (k>>5); inside: halfword offset
//   ((k>>3)&3)*128 + (m&15)*8 + (k&7)
// wave A-fragment read = slot + f*512 + lane*8 (16 B/lane contiguous).

// ---------------------------------------------------------------------------
// Merged precompute: blocks [0,1536) build wmod slots; blocks [1536,1600)
// pack conv weights into slot 0. One launch (saves a dispatch gap).
__global__ __launch_bounds__(256) void prep_kernel(
    const float* __restrict__ y, const float* __restrict__ aw,
    const float* __restrict__ ab, const float* __restrict__ mw,
    const float* __restrict__ cw, unsigned short* __restrict__ wsBF)
{
    int w = threadIdx.x >> 6, lane = threadIdx.x & 63;

    if (blockIdx.x >= 1536) {              // conv-weight packing
        int m = (blockIdx.x - 1536)*4 + w; // 0..255
#pragma unroll
        for (int u = 0; u < 4; ++u) {
            int k = lane + 64*u;
            int f = (m >> 4)*8 + (k >> 5);
            int hw = f*512 + ((k >> 3) & 3)*128 + (m & 15)*8 + (k & 7);
            wsBF[hw] = f2bf(cw[(size_t)m*CC + k]);
        }
        return;
    }

    int r = blockIdx.x*4 + w;      // 0 .. 6143
    int l = r >> 10;
    int b = (r >> 8) & 3;
    int o = r & 255;

    const float* awr = aw + (size_t)(l*CC + o)*SS;
    const float* yb  = y + (size_t)b*SS;
    float s = 0.f;
#pragma unroll
    for (int j = 0; j < 8; ++j) { int idx = lane + 64*j; s += awr[idx]*yb[idx]; }
#pragma unroll
    for (int off = 32; off; off >>= 1) s += __shfl_xor(s, off);
    float t = s + ab[l*CC + o] + 1.0f;

    const float* mwr = mw + (size_t)(l*CC + o)*CC;
    float wv[4]; float ss = 0.f;
#pragma unroll
    for (int u = 0; u < 4; ++u) { int j = lane + 64*u; wv[u] = mwr[j]*t; ss += wv[u]*wv[u]; }
#pragma unroll
    for (int off = 32; off; off >>= 1) ss += __shfl_xor(ss, off);
    float d = 1.0f / sqrtf(ss + 1e-8f);

    unsigned short* slot = wsBF + (size_t)(1 + l*NB + b)*SLOT_HW;
#pragma unroll
    for (int u = 0; u < 4; ++u) {
        int k = lane + 64*u;
        int f = (o >> 4)*8 + (k >> 5);
        int hw = f*512 + ((k >> 3) & 3)*128 + (o & 15)*8 + (k & 7);
        slot[hw] = f2bf(wv[u]*d);
    }
}

// ---------------------------------------------------------------------------
// Fused: one block = (batch, 32-px half-strip, all 256 channels). Grid 512,
// 68 KB LDS -> 2 blocks/CU. Wave w owns m=[32w,32w+32), all n=32 (zero A
// duplication). B plain bf16; state y1/y2 fp32 in regs. Layer B (16 KB)
// double-buffered -> 1 barrier/layer; A L2->reg prefetch depth 4 (r15).
#define BFRAGL(buf, kq, nt, kcl) \
    (lds + (buf)*16384 + ((((kq)*2 + (nt))*2 + (kcl)))*1024)

__global__ __launch_bounds__(512, 4) void fused_kernel(
    const float* __restrict__ x, const float* __restrict__ cb,
    const unsigned short* __restrict__ wsBF, float* __restrict__ out)
{
    // LDS 69632 B: layer-B dbuf [0,32K) | conv region @32768: xS f32[256][36]
    // (36864 B) during conv staging, then S2 f32[128][33] (16896 B) in the
    // epilogue (xS dead by then). Conv B frags live in buf0.
    __shared__ __align__(16) unsigned char lds[69632];
    float* xS = (float*)(lds + 32768);
    float* S2 = (float*)(lds + 32768);

    const int tid  = threadIdx.x;
    const int lane = tid & 63;
    const int w    = tid >> 6;     // wave 0..7: owns m-rows [32w, 32w+32)
    const int l15  = lane & 15;
    const int q    = lane >> 4;    // 0..3

    // XCD swizzle: blockIdx%8 -> (batch, half) per XCD; weights L2-resident
    const int bswz  = blockIdx.x & 7;
    const int b     = bswz >> 1;               // 0..3
    const int half  = bswz & 1;                // 0..1
    const int strip = blockIdx.x >> 3;         // 0..63
    const int n0    = strip * 64 + half * 32;  // 32-px window

    float y1[2][2][4], y2[2][2][4];
    f32x4 acc[2][2];

    // ---------------- conv GEMM:  acc = cw @ x[b], single-shot ----------------
#pragma unroll
    for (int t = 0; t < 2; ++t)
#pragma unroll
        for (int s = 0; s < 2; ++s) acc[t][s] = 0;

    {   // stage FULL x window [256k x 32n] fp32, coalesced
#pragma unroll
        for (int p = 0; p < 4; ++p) {
            int row = (tid >> 3) + 64*p, c4 = (tid & 7) * 4;
            float4 v = *(const float4*)&x[((size_t)(b*CC + row))*4096 + n0 + c4];
            *(float4*)&xS[row*36 + c4] = v;
        }
    }
    __syncthreads();
    {   // transpose-read (conflict-free) -> bf16 -> ALL conv-B frags (buf0)
        int n = tid & 31, k0 = (tid >> 5) * 16;
        int nt = n >> 4, n15 = n & 15;
#pragma unroll
        for (int j = 0; j < 4; ++j) {
            int k = k0 + 4*j;
            u16x4 hv;
#pragma unroll
            for (int i = 0; i < 4; ++i) hv[i] = f2bf(xS[(k+i)*36 + n]);
            int kq = k >> 6, kcl = (k >> 5) & 1, qq = (k >> 3) & 3, jb = k & 7;
            *(u16x4*)(BFRAGL(0,kq,nt,kcl) + (16*qq + n15)*16 + jb*2) = hv;
        }
    }
    {   // A prefetch (slot 0) depth 4, then one 8-step MFMA phase
        const unsigned short* slot = wsBF;
        s16x8 aS[8][2];
#pragma unroll
        for (int p = 0; p < 4; ++p)
#pragma unroll
        for (int t = 0; t < 2; ++t)
            aS[p][t] = *(const s16x8*)(slot + (size_t)(((2*w+t)*8 + p)*512) + lane*8);
        __syncthreads();
#pragma unroll
        for (int step = 0; step < 8; ++step) {
            if (step < 4) {
#pragma unroll
                for (int t = 0; t < 2; ++t)
                    aS[step+4][t] = *(const s16x8*)(slot + (size_t)(((2*w+t)*8 + step+4)*512) + lane*8);
            }
            int kq = step >> 1, kcl = step & 1;
#pragma unroll
            for (int s = 0; s < 2; ++s) {
                s16x8 bh = *(const s16x8*)(BFRAGL(0,kq,s,kcl) + lane*16);
#pragma unroll
                for (int t = 0; t < 2; ++t)
                    acc[t][s] = __builtin_amdgcn_mfma_f32_16x16x32_bf16(aS[step][t], bh, acc[t][s], 0, 0, 0);
            }
        }
    }

    // conv epilogue: bias + channel-duplication remap via S2 (xS region, dead).
    // x1[c] = conv[c>>1]+cb, x2[c] = conv[128+(c>>1)]+cb
#pragma unroll
    for (int pass = 0; pass < 2; ++pass) {
        __syncthreads();
        if ((w >> 2) == pass) {            // waves owning m in [128pass, +128)
#pragma unroll
            for (int t = 0; t < 2; ++t)
#pragma unroll
            for (int s = 0; s < 2; ++s)
#pragma unroll
            for (int r = 0; r < 4; ++r) {
                int m  = 32*w + 16*t + 4*q + r;
                int nl = 16*s + l15;
                S2[(m - 128*pass)*33 + nl] = acc[t][s][r] + cb[m];
            }
        }
        __syncthreads();
#pragma unroll
        for (int t = 0; t < 2; ++t)
#pragma unroll
        for (int s = 0; s < 2; ++s)
#pragma unroll
        for (int r = 0; r < 4; ++r) {
            int c  = 32*w + 16*t + 4*q + r;
            int nl = 16*s + l15;
            float v = S2[(c >> 1)*33 + nl];
            if (pass == 0) { y1[t][s][r] = v; }
            else           { y2[t][s][r] = v; y1[t][s][r] += v; }
        }
    }
    // y1 = x1+x2, y2 = x2.  No barrier needed: layer-0 staging targets buf0
    // [0,16K), disjoint from S2 @32768; buf0's conv reads were fenced by the
    // epilogue's first __syncthreads.

    // ---------------- 6 layers: ONE barrier per layer (B dbuf) ----------------
    for (int l = 0; l < NL; ++l) {
        const int buf = l & 1;
        const unsigned short* slot = wsBF + (size_t)(1 + l*NB + b)*SLOT_HW;
#pragma unroll
        for (int t = 0; t < 2; ++t)
#pragma unroll
            for (int s = 0; s < 2; ++s) acc[t][s] = 0;

        // stage B (bf16) from y1 regs: wave w's rows = k-slice [32w,32w+32)
        {
            int kq = w >> 1, kcl = w & 1, jb = 4*(q & 1);
#pragma unroll
            for (int t = 0; t < 2; ++t) {
                int qq = 2*t + (q >> 1);
#pragma unroll
                for (int s = 0; s < 2; ++s) {
                    u16x4 hv;
#pragma unroll
                    for (int r = 0; r < 4; ++r) hv[r] = f2bf(y1[t][s][r]);
                    *(u16x4*)(BFRAGL(buf,kq,s,kcl) + (16*qq + l15)*16 + jb*2) = hv;
                }
            }
        }
        // A prefetch pipeline, depth 4: issue steps 0..3 before the barrier
        s16x8 aS[8][2];
#pragma unroll
        for (int p = 0; p < 4; ++p)
#pragma unroll
        for (int t = 0; t < 2; ++t)
            aS[p][t] = *(const s16x8*)(slot + (size_t)(((2*w+t)*8 + p)*512) + lane*8);
        __syncthreads();
        // ONE long MFMA phase: 8 steps, A prefetched 4 steps ahead
#pragma unroll
        for (int step = 0; step < 8; ++step) {
            if (step < 4) {
#pragma unroll
                for (int t = 0; t < 2; ++t)
                    aS[step+4][t] = *(const s16x8*)(slot + (size_t)(((2*w+t)*8 + step+4)*512) + lane*8);
            }
            int kq = step >> 1, kcl = step & 1;
#pragma unroll
            for (int s = 0; s < 2; ++s) {
                s16x8 bh = *(const s16x8*)(BFRAGL(buf,kq,s,kcl) + lane*16);
#pragma unroll
                for (int t = 0; t < 2; ++t)
                    acc[t][s] = __builtin_amdgcn_mfma_f32_16x16x32_bf16(aS[step][t], bh, acc[t][s], 0, 0, 0);
            }
        }
        // y2 += gelu(h); y1 += y2 (next layer), skip on last.
        // No trailing barrier: next layer stages the OTHER buffer.
#pragma unroll
        for (int t = 0; t < 2; ++t)
#pragma unroll
        for (int s = 0; s < 2; ++s)
#pragma unroll
        for (int r = 0; r < 4; ++r) {
            y2[t][s][r] += gelu_fast(acc[t][s][r]);
            if (l < NL - 1) y1[t][s][r] += y2[t][s][r];
        }
    }

    // ---------------- out = 0.5*(y1+y2), 2x2 upsample (nontemporal) --------
#pragma unroll
    for (int t = 0; t < 2; ++t)
#pragma unroll
    for (int s = 0; s < 2; ++s)
#pragma unroll
    for (int r = 0; r < 4; ++r) {
        int ch  = 32*w + 16*t + 4*q + r;
        int wpx = half*32 + 16*s + l15;       // 0..63 source col
        float v = 0.5f*(y1[t][s][r] + y2[t][s][r]);
        f32x2 vv = {v, v};
        size_t base = (((size_t)(b*CC + ch)*128 + 2*strip))*128 + 2*wpx;
        __builtin_nontemporal_store(vv, (f32x2*)&out[base]);
        __builtin_nontemporal_store(vv, (f32x2*)&out[base + 128]);
    }
}

extern "C" void kernel_launch(void* const* d_in, const int* in_sizes, int n_in,
                              void* d_out, int out_size, void* d_ws, size_t ws_size,
                              hipStream_t stream) {
    const float* x  = (const float*)d_in[0];
    const float* y  = (const float*)d_in[1];
    const float* cw = (const float*)d_in[2];
    const float* cb = (const float*)d_in[3];
    const float* aw = (const float*)d_in[4];
    const float* ab = (const float*)d_in[5];
    const float* mw = (const float*)d_in[6];
    float* out = (float*)d_out;

    unsigned short* wsBF = (unsigned short*)d_ws;   // 25 slots * 128 KB = 3.2 MB

    prep_kernel<<<1600, 256, 0, stream>>>(y, aw, ab, mw, cw, wsBF);
    fused_kernel<<<512, 512, 0, stream>>>(x, cb, wsBF, out);
}